// Round 1
// baseline (111.450 us; speedup 1.0000x reference)
//
#include <hip/hip_runtime.h>
#include <hip/hip_bf16.h>
#include <stdint.h>
#include <type_traits>

// Problem constants (fixed shapes from the reference)
constexpr int NA   = 10000;  // atoms
constexpr int NH   = 75;     // hidden
constexpr int NPF  = 14;     // pair features
constexpr int NW   = 5625;   // 75*75
constexpr int NCOL = 1200;   // 75 * 16  (per (h): f=0..13 W-cols, f=14 bias, f=15 pad)
constexpr int KPAD = 80;     // 75 padded to 80 for clean k-loop / alignment

// ---------- K0: build rowstart (CSR) from sorted atom_to_pair[:,0] ----------
__global__ void k_rowstart(const int* __restrict__ atp, int* __restrict__ rs, int E) {
    int e = blockIdx.x * blockDim.x + threadIdx.x;
    if (e >= E) return;
    int c  = atp[2 * e];
    int cp = (e == 0) ? -1 : atp[2 * (e - 1)];
    for (int a = cp + 1; a <= c; ++a) rs[a] = e;
    if (e == E - 1)
        for (int a = c + 1; a <= NA; ++a) rs[a] = E;
}

__device__ inline uint32_t f2bf_bits(float f) {
    uint32_t u = __float_as_uint(f);
    uint32_t r = u + 0x7fffu + ((u >> 16) & 1u);   // RNE
    return r >> 16;
}

// ---------- K1: U[a][c] = sum_k af[a][k] * Wcol(c)[k] ----------
// c = h*16 + f;  f<14 -> W[f][h*75+k], f==14 -> b[h*75+k], f==15 -> 0
template <typename TU>
__global__ __launch_bounds__(256) void k_buildU(
    const float* __restrict__ af, const float* __restrict__ W,
    const float* __restrict__ bias, TU* __restrict__ U)
{
    __shared__ float As[64][84];   // [atom][k], row stride 84 -> 2-way-max bank aliasing on reads
    __shared__ float Bs[KPAD][68]; // [k][col],  stride 68 -> aligned float4, benign banks

    const int a0 = blockIdx.y * 64;
    const int c0 = blockIdx.x * 64;
    const int tid = threadIdx.x;

    // Stage A: coalesced global read, conflict-free LDS write (lanes -> consecutive k)
    for (int i = tid; i < 64 * KPAD; i += 256) {
        int a = i / KPAD, k = i - a * KPAD;
        int ga = a0 + a;
        float v = 0.f;
        if (ga < NA && k < NH) v = af[ga * NH + k];
        As[a][k] = v;
    }
    // Stage B: k-major; lanes write consecutive cols (conflict-free), W reads are L2-hot
    for (int i = tid; i < 64 * KPAD; i += 256) {
        int k = i >> 6, c = i & 63;
        int gc = c0 + c;
        float v = 0.f;
        if (gc < NCOL && k < NH) {
            int h = gc >> 4, f = gc & 15;
            if (f < NPF)       v = W[f * NW + h * NH + k];
            else if (f == NPF) v = bias[h * NH + k];
        }
        Bs[k][c] = v;
    }
    __syncthreads();

    const int tm = tid >> 4, tn = tid & 15;  // 16x16 threads of 4x4 microtiles
    float acc[4][4] = {};

    for (int k = 0; k < KPAD; k += 4) {
        float4 a4[4], b4[4];
        #pragma unroll
        for (int i = 0; i < 4; ++i)
            a4[i] = *(const float4*)&As[tm * 4 + i][k];     // atom i, k..k+3
        #pragma unroll
        for (int kk = 0; kk < 4; ++kk)
            b4[kk] = *(const float4*)&Bs[k + kk][tn * 4];   // cols 4tn..+3 at k+kk
        #pragma unroll
        for (int i = 0; i < 4; ++i) {
            float av[4] = {a4[i].x, a4[i].y, a4[i].z, a4[i].w};
            #pragma unroll
            for (int kk = 0; kk < 4; ++kk) {
                acc[i][0] += av[kk] * b4[kk].x;
                acc[i][1] += av[kk] * b4[kk].y;
                acc[i][2] += av[kk] * b4[kk].z;
                acc[i][3] += av[kk] * b4[kk].w;
            }
        }
    }

    // Store 4x float4 (or packed bf16x4) per thread
    const int cbase = c0 + tn * 4;
    if (cbase < NCOL) {
        #pragma unroll
        for (int i = 0; i < 4; ++i) {
            int ga = a0 + tm * 4 + i;
            if (ga >= NA) break;
            if constexpr (std::is_same<TU, float>::value) {
                float4 st = make_float4(acc[i][0], acc[i][1], acc[i][2], acc[i][3]);
                *(float4*)&U[(size_t)ga * NCOL + cbase] = st;
            } else {
                ushort4 st;
                st.x = (unsigned short)f2bf_bits(acc[i][0]);
                st.y = (unsigned short)f2bf_bits(acc[i][1]);
                st.z = (unsigned short)f2bf_bits(acc[i][2]);
                st.w = (unsigned short)f2bf_bits(acc[i][3]);
                *(ushort4*)&U[(size_t)ga * NCOL + cbase] = st;
            }
        }
    }
}

__device__ inline float bf_lo(uint32_t w) { return __uint_as_float(w << 16); }
__device__ inline float bf_hi(uint32_t w) { return __uint_as_float(w & 0xffff0000u); }

// ---------- K2: per-(atom,h) edge loop + reduce (no atomics; rowstart ranges) ----------
template <typename TU>
__global__ __launch_bounds__(256) void k_edges(
    const float* __restrict__ pf, const int* __restrict__ atp,
    const int* __restrict__ rs, const TU* __restrict__ U,
    float* __restrict__ out)
{
    int idx = blockIdx.x * blockDim.x + threadIdx.x;
    if (idx >= NA * NH) return;
    int a = idx / NH;
    int h = idx - a * NH;
    int e0 = rs[a], e1 = rs[a + 1];

    float acc = 0.f;
    for (int e = e0; e < e1; ++e) {
        int a1 = atp[2 * e + 1];
        const float* pfe = pf + (size_t)e * NPF;
        float p[14];
        #pragma unroll
        for (int f = 0; f < 7; ++f) {      // pf rows are 8B aligned (14 floats)
            float2 t = *(const float2*)&pfe[2 * f];
            p[2 * f] = t.x; p[2 * f + 1] = t.y;
        }
        float s;
        if constexpr (std::is_same<TU, float>::value) {
            const float4* u = (const float4*)&U[(size_t)a1 * NCOL + h * 16];
            float4 u0 = u[0], u1 = u[1], u2 = u[2], u3 = u[3];
            s  = u3.z;                         // f=14: bias-matvec term, coeff 1
            s += p[0]  * u0.x; s += p[1]  * u0.y; s += p[2]  * u0.z; s += p[3]  * u0.w;
            s += p[4]  * u1.x; s += p[5]  * u1.y; s += p[6]  * u1.z; s += p[7]  * u1.w;
            s += p[8]  * u2.x; s += p[9]  * u2.y; s += p[10] * u2.z; s += p[11] * u2.w;
            s += p[12] * u3.x; s += p[13] * u3.y;
        } else {
            const uint32_t* up = (const uint32_t*)(U + (size_t)a1 * NCOL + h * 16);
            uint32_t w0 = up[0], w1 = up[1], w2 = up[2], w3 = up[3];
            uint32_t w4 = up[4], w5 = up[5], w6 = up[6], w7 = up[7];
            s  = bf_lo(w7);                    // f=14
            s += p[0]  * bf_lo(w0); s += p[1]  * bf_hi(w0);
            s += p[2]  * bf_lo(w1); s += p[3]  * bf_hi(w1);
            s += p[4]  * bf_lo(w2); s += p[5]  * bf_hi(w2);
            s += p[6]  * bf_lo(w3); s += p[7]  * bf_hi(w3);
            s += p[8]  * bf_lo(w4); s += p[9]  * bf_hi(w4);
            s += p[10] * bf_lo(w5); s += p[11] * bf_hi(w5);
            s += p[12] * bf_lo(w6); s += p[13] * bf_hi(w6);
        }
        acc += s;
    }
    out[idx] = acc;
}

// ---------- Fallback: direct per-(edge,h) compute with atomics (tiny ws) ----------
__global__ void k_naive(const float* __restrict__ pf, const float* __restrict__ af,
                        const int* __restrict__ atp, const float* __restrict__ W,
                        const float* __restrict__ bias, float* __restrict__ out, int E)
{
    int idx = blockIdx.x * blockDim.x + threadIdx.x;
    if (idx >= E * NH) return;
    int e = idx / NH, h = idx - e * NH;
    int a0 = atp[2 * e], a1 = atp[2 * e + 1];
    float p[NPF];
    #pragma unroll
    for (int f = 0; f < NPF; ++f) p[f] = pf[(size_t)e * NPF + f];
    float acc = 0.f;
    for (int k = 0; k < NH; ++k) {
        float w = bias[h * NH + k];
        #pragma unroll
        for (int f = 0; f < NPF; ++f) w += p[f] * W[f * NW + h * NH + k];
        acc += w * af[a1 * NH + k];
    }
    atomicAdd(&out[a0 * NH + h], acc);
}

extern "C" void kernel_launch(void* const* d_in, const int* in_sizes, int n_in,
                              void* d_out, int out_size, void* d_ws, size_t ws_size,
                              hipStream_t stream) {
    const float* pf   = (const float*)d_in[0];
    const float* af   = (const float*)d_in[1];
    const int*   atp  = (const int*)d_in[2];
    const float* W    = (const float*)d_in[3];
    const float* bias = (const float*)d_in[4];
    float* out = (float*)d_out;
    const int E = in_sizes[2] / 2;

    const size_t uF  = (size_t)NA * NCOL * sizeof(float);
    const size_t uB  = (size_t)NA * NCOL * sizeof(unsigned short);
    const size_t rsB = (size_t)(NA + 1) * sizeof(int);

    if (ws_size >= uF + rsB) {
        float* U = (float*)d_ws;
        int*  rs = (int*)((char*)d_ws + uF);
        k_rowstart<<<(E + 255) / 256, 256, 0, stream>>>(atp, rs, E);
        dim3 g1((NCOL + 63) / 64, (NA + 63) / 64);
        k_buildU<float><<<g1, 256, 0, stream>>>(af, W, bias, U);
        k_edges<float><<<(NA * NH + 255) / 256, 256, 0, stream>>>(pf, atp, rs, U, out);
    } else if (ws_size >= uB + rsB) {
        __hip_bfloat16* U = (__hip_bfloat16*)d_ws;
        int* rs = (int*)((char*)d_ws + uB);
        k_rowstart<<<(E + 255) / 256, 256, 0, stream>>>(atp, rs, E);
        dim3 g1((NCOL + 63) / 64, (NA + 63) / 64);
        k_buildU<__hip_bfloat16><<<g1, 256, 0, stream>>>(af, W, bias, U);
        k_edges<__hip_bfloat16><<<(NA * NH + 255) / 256, 256, 0, stream>>>(pf, atp, rs, U, out);
    } else {
        hipMemsetAsync(d_out, 0, (size_t)out_size * sizeof(float), stream);
        k_naive<<<((size_t)E * NH + 255) / 256, 256, 0, stream>>>(pf, af, atp, W, bias, out, E);
    }
}

// Round 2
// 51.181 us; speedup vs baseline: 2.1776x; 2.1776x over previous
//
#include <hip/hip_runtime.h>
#include <hip/hip_bf16.h>
#include <stdint.h>

// Problem constants
constexpr int NA   = 10000;  // atoms
constexpr int NH   = 75;     // hidden
constexpr int NPF  = 14;     // pair features
constexpr int NW   = 5625;   // 75*75
constexpr int NCOL = 1200;   // 75*16: per h -> f=0..13 W-cols, f=14 bias, f=15 pad
constexpr int KP   = 104;    // K padded: 75 data, zeros to 96 (3 MFMA k-steps), 104 for stride
constexpr int MROW = 10112;  // NA padded to 79*128
constexpr int WROW = 1208;   // NCOL padded rows for staging slack

typedef __attribute__((ext_vector_type(8))) __bf16 bf16x8;
typedef __attribute__((ext_vector_type(4))) float floatx4;

__device__ __forceinline__ uint32_t f2bf_bits(float f) {
    uint32_t u = __float_as_uint(f);
    return (u + 0x7fffu + ((u >> 16) & 1u)) >> 16;   // RNE
}
__device__ __forceinline__ float bf_lo(uint32_t w) { return __uint_as_float(w << 16); }
__device__ __forceinline__ float bf_hi(uint32_t w) { return __uint_as_float(w & 0xffff0000u); }

__device__ __forceinline__ void gload16(const void* g, void* l) {
    __builtin_amdgcn_global_load_lds(
        (const __attribute__((address_space(1))) uint32_t*)g,
        (__attribute__((address_space(3))) uint32_t*)l, 16, 0, 0);
}

// ---------- K0: rowstart CSR from sorted atom_to_pair[:,0] ----------
__global__ void k_rowstart(const int* __restrict__ atp, int* __restrict__ rs, int E) {
    int e = blockIdx.x * blockDim.x + threadIdx.x;
    if (e >= E) return;
    int c  = atp[2 * e];
    int cp = (e == 0) ? -1 : atp[2 * (e - 1)];
    for (int a = cp + 1; a <= c; ++a) rs[a] = e;
    if (e == E - 1)
        for (int a = c + 1; a <= NA; ++a) rs[a] = E;
}

// ---------- convert af -> bf16 [MROW][KP], zero padded ----------
__global__ __launch_bounds__(256) void k_cvt_af(const float* __restrict__ af,
                                                ushort* __restrict__ afb) {
    int idx = blockIdx.x * blockDim.x + threadIdx.x;   // over MROW*26 quads
    if (idx >= MROW * (KP / 4)) return;
    int a = idx / (KP / 4), q = idx - a * (KP / 4);
    int k0 = q * 4;
    ushort4 st = {0, 0, 0, 0};
    if (a < NA) {
        float v[4];
        #pragma unroll
        for (int j = 0; j < 4; ++j) {
            int k = k0 + j;
            v[j] = (k < NH) ? af[a * NH + k] : 0.f;
        }
        st.x = (ushort)f2bf_bits(v[0]); st.y = (ushort)f2bf_bits(v[1]);
        st.z = (ushort)f2bf_bits(v[2]); st.w = (ushort)f2bf_bits(v[3]);
    }
    ((ushort4*)afb)[idx] = st;
}

// ---------- build Wbt[c][k] bf16, c = h*16+f (N-major so B-frags are contiguous) ----------
__global__ __launch_bounds__(256) void k_cvt_w(const float* __restrict__ W,
                                               const float* __restrict__ bias,
                                               ushort* __restrict__ wbt) {
    int idx = blockIdx.x * blockDim.x + threadIdx.x;   // over WROW*26 quads
    if (idx >= WROW * (KP / 4)) return;
    int c = idx / (KP / 4), q = idx - c * (KP / 4);
    int k0 = q * 4;
    ushort4 st = {0, 0, 0, 0};
    if (c < NCOL) {
        int h = c >> 4, f = c & 15;
        float v[4] = {0.f, 0.f, 0.f, 0.f};
        #pragma unroll
        for (int j = 0; j < 4; ++j) {
            int k = k0 + j;
            if (k < NH) {
                if (f < NPF)       v[j] = W[f * NW + h * NH + k];
                else if (f == NPF) v[j] = bias[h * NH + k];
            }
        }
        st.x = (ushort)f2bf_bits(v[0]); st.y = (ushort)f2bf_bits(v[1]);
        st.z = (ushort)f2bf_bits(v[2]); st.w = (ushort)f2bf_bits(v[3]);
    }
    ((ushort4*)wbt)[idx] = st;
}

// ---------- K1: MFMA GEMM  U[a][c] = sum_k afb[a][k]*Wbt[c][k], U stored bf16 ----------
// Tile 128x80, 4 waves: wave w owns rows w*32..+31 (2 m-frags) x 80 cols (5 n-frags).
__global__ __launch_bounds__(256) void k_gemm(const ushort* __restrict__ afb,
                                              const ushort* __restrict__ wbt,
                                              ushort* __restrict__ U) {
    __shared__ __align__(16) ushort sm[22016];         // 26624B A + 17408B B
    ushort* As = sm;                                   // [128][104]
    ushort* Bs = sm + 13312;                           // [80+pad][104]

    const int tid  = threadIdx.x;
    const int lane = tid & 63, wid = tid >> 6;
    const int a0 = blockIdx.y * 128;
    const int c0 = blockIdx.x * 80;

    const char* aSrc = (const char*)(afb + (size_t)a0 * KP);  // 26624B contiguous
    const char* bSrc = (const char*)(wbt + (size_t)c0 * KP);  // 16640B (+slack) contiguous

    // stage: 26 A-chunks + 17 B-chunks of 1024B (64 lanes x 16B), wave-uniform LDS dest
    for (int c = wid; c < 43; c += 4) {
        if (c < 26) gload16(aSrc + c * 1024 + lane * 16, (char*)As + c * 1024);
        else {
            int cb = c - 26;
            gload16(bSrc + cb * 1024 + lane * 16, (char*)Bs + cb * 1024);
        }
    }
    __syncthreads();   // compiler emits vmcnt(0) drain before s_barrier

    const int lr = lane & 15;          // frag row/col
    const int lk = (lane >> 4) * 8;    // frag k-base
    floatx4 acc[2][5] = {};

    #pragma unroll
    for (int ks = 0; ks < 3; ++ks) {
        bf16x8 a[2], b[5];
        #pragma unroll
        for (int mf = 0; mf < 2; ++mf)
            a[mf] = *(const bf16x8*)&As[(wid * 32 + mf * 16 + lr) * KP + ks * 32 + lk];
        #pragma unroll
        for (int nf = 0; nf < 5; ++nf)
            b[nf] = *(const bf16x8*)&Bs[(nf * 16 + lr) * KP + ks * 32 + lk];
        #pragma unroll
        for (int mf = 0; mf < 2; ++mf)
            #pragma unroll
            for (int nf = 0; nf < 5; ++nf)
                acc[mf][nf] = __builtin_amdgcn_mfma_f32_16x16x32_bf16(
                    a[mf], b[nf], acc[mf][nf], 0, 0, 0);
    }

    // C/D layout: col = lane&15, row = (lane>>4)*4 + reg  [verified mapping]
    #pragma unroll
    for (int mf = 0; mf < 2; ++mf) {
        #pragma unroll
        for (int nf = 0; nf < 5; ++nf) {
            int col = c0 + nf * 16 + lr;
            #pragma unroll
            for (int r = 0; r < 4; ++r) {
                int row = a0 + wid * 32 + mf * 16 + (lane >> 4) * 4 + r;
                if (row < NA)
                    U[(size_t)row * NCOL + col] = (ushort)f2bf_bits(acc[mf][nf][r]);
            }
        }
    }
}

// ---------- K2: per-(atom,h) edge loop, no atomics ----------
__global__ __launch_bounds__(256) void k_edges_bf(
    const float* __restrict__ pf, const int* __restrict__ atp,
    const int* __restrict__ rs, const ushort* __restrict__ U,
    float* __restrict__ out)
{
    int idx = blockIdx.x * blockDim.x + threadIdx.x;
    if (idx >= NA * NH) return;
    int a = idx / NH;
    int h = idx - a * NH;
    int e0 = rs[a], e1 = rs[a + 1];

    float acc = 0.f;
    for (int e = e0; e < e1; ++e) {
        int a1 = atp[2 * e + 1];
        const float* pfe = pf + (size_t)e * NPF;
        float p[14];
        #pragma unroll
        for (int f = 0; f < 7; ++f) {
            float2 t = *(const float2*)&pfe[2 * f];
            p[2 * f] = t.x; p[2 * f + 1] = t.y;
        }
        const uint4* up = (const uint4*)(U + (size_t)a1 * NCOL + h * 16);
        uint4 q0 = up[0], q1 = up[1];
        float s = bf_lo(q1.w);                     // f=14 bias-matvec term
        s += p[0]  * bf_lo(q0.x); s += p[1]  * bf_hi(q0.x);
        s += p[2]  * bf_lo(q0.y); s += p[3]  * bf_hi(q0.y);
        s += p[4]  * bf_lo(q0.z); s += p[5]  * bf_hi(q0.z);
        s += p[6]  * bf_lo(q0.w); s += p[7]  * bf_hi(q0.w);
        s += p[8]  * bf_lo(q1.x); s += p[9]  * bf_hi(q1.x);
        s += p[10] * bf_lo(q1.y); s += p[11] * bf_hi(q1.y);
        s += p[12] * bf_lo(q1.z); s += p[13] * bf_hi(q1.z);
        acc += s;
    }
    out[idx] = acc;
}

// ---------- Fallback: direct per-(edge,h) with atomics ----------
__global__ void k_naive(const float* __restrict__ pf, const float* __restrict__ af,
                        const int* __restrict__ atp, const float* __restrict__ W,
                        const float* __restrict__ bias, float* __restrict__ out, int E)
{
    int idx = blockIdx.x * blockDim.x + threadIdx.x;
    if (idx >= E * NH) return;
    int e = idx / NH, h = idx - e * NH;
    int a0 = atp[2 * e], a1 = atp[2 * e + 1];
    float p[NPF];
    #pragma unroll
    for (int f = 0; f < NPF; ++f) p[f] = pf[(size_t)e * NPF + f];
    float acc = 0.f;
    for (int k = 0; k < NH; ++k) {
        float w = bias[h * NH + k];
        #pragma unroll
        for (int f = 0; f < NPF; ++f) w += p[f] * W[f * NW + h * NH + k];
        acc += w * af[a1 * NH + k];
    }
    atomicAdd(&out[a0 * NH + h], acc);
}

extern "C" void kernel_launch(void* const* d_in, const int* in_sizes, int n_in,
                              void* d_out, int out_size, void* d_ws, size_t ws_size,
                              hipStream_t stream) {
    const float* pf   = (const float*)d_in[0];
    const float* af   = (const float*)d_in[1];
    const int*   atp  = (const int*)d_in[2];
    const float* W    = (const float*)d_in[3];
    const float* bias = (const float*)d_in[4];
    float* out = (float*)d_out;
    const int E = in_sizes[2] / 2;

    const size_t offAfb = 0;
    const size_t offWbt = offAfb + (size_t)MROW * KP * 2;        // 2,103,296
    const size_t offU   = offWbt + (size_t)WROW * KP * 2;        // +251,264
    const size_t offRs  = offU + (size_t)NA * NCOL * 2;          // +24,000,000
    const size_t need   = offRs + (size_t)(NA + 1) * sizeof(int);

    if (ws_size >= need) {
        ushort* afb = (ushort*)((char*)d_ws + offAfb);
        ushort* wbt = (ushort*)((char*)d_ws + offWbt);
        ushort* U   = (ushort*)((char*)d_ws + offU);
        int*    rs  = (int*)((char*)d_ws + offRs);

        k_rowstart<<<(E + 255) / 256, 256, 0, stream>>>(atp, rs, E);
        k_cvt_af<<<(MROW * (KP / 4) + 255) / 256, 256, 0, stream>>>(af, afb);
        k_cvt_w<<<(WROW * (KP / 4) + 255) / 256, 256, 0, stream>>>(W, bias, wbt);
        dim3 g1(NCOL / 80, MROW / 128);   // 15 x 79
        k_gemm<<<g1, 256, 0, stream>>>(afb, wbt, U);
        k_edges_bf<<<(NA * NH + 255) / 256, 256, 0, stream>>>(pf, atp, rs, U, out);
    } else {
        hipMemsetAsync(d_out, 0, (size_t)out_size * sizeof(float), stream);
        k_naive<<<((size_t)E * NH + 255) / 256, 256, 0, stream>>>(pf, af, atp, W, bias, out, E);
    }
}

// Round 3
// 41.482 us; speedup vs baseline: 2.6867x; 1.2338x over previous
//
#include <hip/hip_runtime.h>
#include <hip/hip_bf16.h>
#include <stdint.h>

// Problem constants
constexpr int NA   = 10000;  // atoms
constexpr int NH   = 75;     // hidden
constexpr int NPF  = 14;     // pair features
constexpr int NW   = 5625;   // 75*75
constexpr int NCOL = 1200;   // 75*16: per h -> f=0..13 W-cols, f=14 bias, f=15 pad
constexpr int KP   = 104;    // K padded: 75 data, zeros to 96 (3 MFMA k-steps), 104 stride
constexpr int MROW = 10112;  // NA padded to 79*128
constexpr int WROW = 1208;   // NCOL padded rows for staging slack
constexpr int JSL  = 38;     // h-slots per atom in k_edges (thread does h=j and h=j+38)

typedef __attribute__((ext_vector_type(8))) __bf16 bf16x8;
typedef __attribute__((ext_vector_type(4))) float floatx4;

__device__ __forceinline__ uint32_t f2bf_bits(float f) {
    uint32_t u = __float_as_uint(f);
    return (u + 0x7fffu + ((u >> 16) & 1u)) >> 16;   // RNE
}
__device__ __forceinline__ float bf_lo(uint32_t w) { return __uint_as_float(w << 16); }
__device__ __forceinline__ float bf_hi(uint32_t w) { return __uint_as_float(w & 0xffff0000u); }

__device__ __forceinline__ void gload16(const void* g, void* l) {
    __builtin_amdgcn_global_load_lds(
        (const __attribute__((address_space(1))) uint32_t*)g,
        (__attribute__((address_space(3))) uint32_t*)l, 16, 0, 0);
}

// ---------- K0: fused prep: cvt_af | cvt_w | rowstart, split by blockIdx ----------
__global__ __launch_bounds__(256) void k_prep(
    const float* __restrict__ af, const float* __restrict__ W,
    const float* __restrict__ bias, const int* __restrict__ atp,
    ushort* __restrict__ afb, ushort* __restrict__ wbt, int* __restrict__ rs,
    int E, int bA, int bW)
{
    const int b = blockIdx.x, tid = threadIdx.x;
    if (b < bA) {
        // convert af -> bf16 [MROW][KP], zero padded
        int idx = b * 256 + tid;
        if (idx >= MROW * (KP / 4)) return;
        int a = idx / (KP / 4), q = idx - a * (KP / 4);
        int k0 = q * 4;
        ushort4 st = {0, 0, 0, 0};
        if (a < NA) {
            float v[4];
            #pragma unroll
            for (int j = 0; j < 4; ++j) {
                int k = k0 + j;
                v[j] = (k < NH) ? af[a * NH + k] : 0.f;
            }
            st.x = (ushort)f2bf_bits(v[0]); st.y = (ushort)f2bf_bits(v[1]);
            st.z = (ushort)f2bf_bits(v[2]); st.w = (ushort)f2bf_bits(v[3]);
        }
        ((ushort4*)afb)[idx] = st;
    } else if (b < bA + bW) {
        // build Wbt[c][k] bf16, c = h*16+f (N-major)
        int idx = (b - bA) * 256 + tid;
        if (idx >= WROW * (KP / 4)) return;
        int c = idx / (KP / 4), q = idx - c * (KP / 4);
        int k0 = q * 4;
        ushort4 st = {0, 0, 0, 0};
        if (c < NCOL) {
            int h = c >> 4, f = c & 15;
            float v[4] = {0.f, 0.f, 0.f, 0.f};
            #pragma unroll
            for (int j = 0; j < 4; ++j) {
                int k = k0 + j;
                if (k < NH) {
                    if (f < NPF)       v[j] = W[f * NW + h * NH + k];
                    else if (f == NPF) v[j] = bias[h * NH + k];
                }
            }
            st.x = (ushort)f2bf_bits(v[0]); st.y = (ushort)f2bf_bits(v[1]);
            st.z = (ushort)f2bf_bits(v[2]); st.w = (ushort)f2bf_bits(v[3]);
        }
        ((ushort4*)wbt)[idx] = st;
    } else {
        // rowstart CSR from sorted atom_to_pair[:,0]
        int e = (b - bA - bW) * 256 + tid;
        if (e >= E) return;
        int c  = atp[2 * e];
        int cp = (e == 0) ? -1 : atp[2 * (e - 1)];
        for (int a = cp + 1; a <= c; ++a) rs[a] = e;
        if (e == E - 1)
            for (int a = c + 1; a <= NA; ++a) rs[a] = E;
    }
}

// ---------- K1: MFMA GEMM  U[a][c] = sum_k afb[a][k]*Wbt[c][k], U stored bf16 ----------
// Tile 128x80, 4 waves: wave w owns rows w*32..+31 (2 a-frags) x 80 cols (5 c-frags).
// Operand order mfma(w_frag, a_frag): D col (lane&15) = a-dim, D reg-axis = c-dim
// -> 4 consecutive c per thread -> one 8B ushort4 store per fragment.
__global__ __launch_bounds__(256) void k_gemm(const ushort* __restrict__ afb,
                                              const ushort* __restrict__ wbt,
                                              ushort* __restrict__ U) {
    __shared__ __align__(16) ushort sm[22016];         // 26624B A + 17408B B
    ushort* As = sm;                                   // [128][104]
    ushort* Bs = sm + 13312;                           // [~84][104]

    const int tid  = threadIdx.x;
    const int lane = tid & 63, wid = tid >> 6;
    const int a0 = blockIdx.y * 128;
    const int c0 = blockIdx.x * 80;

    const char* aSrc = (const char*)(afb + (size_t)a0 * KP);  // 26624B contiguous
    const char* bSrc = (const char*)(wbt + (size_t)c0 * KP);  // 17408B (w/ slack)

    // stage: 26 A-chunks + 17 B-chunks of 1024B (64 lanes x 16B), wave-uniform dest
    for (int c = wid; c < 43; c += 4) {
        if (c < 26) gload16(aSrc + c * 1024 + lane * 16, (char*)As + c * 1024);
        else {
            int cb = c - 26;
            gload16(bSrc + cb * 1024 + lane * 16, (char*)Bs + cb * 1024);
        }
    }
    __syncthreads();

    const int lr = lane & 15;          // frag row (A: a-row / W: c-row); D col
    const int lk = (lane >> 4) * 8;    // frag k-base
    floatx4 acc[5][2] = {};

    #pragma unroll
    for (int ks = 0; ks < 3; ++ks) {
        bf16x8 a[2], b[5];
        #pragma unroll
        for (int mf = 0; mf < 2; ++mf)
            a[mf] = *(const bf16x8*)&As[(wid * 32 + mf * 16 + lr) * KP + ks * 32 + lk];
        #pragma unroll
        for (int nf = 0; nf < 5; ++nf)
            b[nf] = *(const bf16x8*)&Bs[(nf * 16 + lr) * KP + ks * 32 + lk];
        #pragma unroll
        for (int nf = 0; nf < 5; ++nf)
            #pragma unroll
            for (int mf = 0; mf < 2; ++mf)
                acc[nf][mf] = __builtin_amdgcn_mfma_f32_16x16x32_bf16(
                    b[nf], a[mf], acc[nf][mf], 0, 0, 0);
    }

    // D: col=lane&15 -> a-row; row=(lane>>4)*4+reg -> c-col (consecutive per reg)
    #pragma unroll
    for (int mf = 0; mf < 2; ++mf) {
        int arow = a0 + wid * 32 + mf * 16 + lr;
        if (arow >= NA) continue;
        #pragma unroll
        for (int nf = 0; nf < 5; ++nf) {
            int cbase = c0 + nf * 16 + (lane >> 4) * 4;
            ushort4 st;
            st.x = (ushort)f2bf_bits(acc[nf][mf][0]);
            st.y = (ushort)f2bf_bits(acc[nf][mf][1]);
            st.z = (ushort)f2bf_bits(acc[nf][mf][2]);
            st.w = (ushort)f2bf_bits(acc[nf][mf][3]);
            *(ushort4*)&U[(size_t)arow * NCOL + cbase] = st;
        }
    }
}

// ---------- K2: per-(atom, j) edge loop; thread handles h=j and h=j+38 ----------
__global__ __launch_bounds__(256) void k_edges2(
    const float* __restrict__ pf, const int* __restrict__ atp,
    const int* __restrict__ rs, const ushort* __restrict__ U,
    float* __restrict__ out)
{
    int idx = blockIdx.x * blockDim.x + threadIdx.x;
    if (idx >= NA * JSL) return;
    int a = idx / JSL;
    int j = idx - a * JSL;
    const bool two = (j + JSL) < NH;   // j < 37
    int e0 = rs[a], e1 = rs[a + 1];

    float acc0 = 0.f, acc1 = 0.f;
    for (int e = e0; e < e1; ++e) {
        int a1 = atp[2 * e + 1];
        const float* pfe = pf + (size_t)e * NPF;
        float p[14];
        #pragma unroll
        for (int f = 0; f < 7; ++f) {
            float2 t = *(const float2*)&pfe[2 * f];
            p[2 * f] = t.x; p[2 * f + 1] = t.y;
        }
        const ushort* ub = U + (size_t)a1 * NCOL;
        {
            const uint4* up = (const uint4*)(ub + j * 16);
            uint4 q0 = up[0], q1 = up[1];
            float s = bf_lo(q1.w);                 // f=14 bias-matvec term
            s += p[0]  * bf_lo(q0.x); s += p[1]  * bf_hi(q0.x);
            s += p[2]  * bf_lo(q0.y); s += p[3]  * bf_hi(q0.y);
            s += p[4]  * bf_lo(q0.z); s += p[5]  * bf_hi(q0.z);
            s += p[6]  * bf_lo(q0.w); s += p[7]  * bf_hi(q0.w);
            s += p[8]  * bf_lo(q1.x); s += p[9]  * bf_hi(q1.x);
            s += p[10] * bf_lo(q1.y); s += p[11] * bf_hi(q1.y);
            s += p[12] * bf_lo(q1.z); s += p[13] * bf_hi(q1.z);
            acc0 += s;
        }
        if (two) {
            const uint4* up = (const uint4*)(ub + (j + JSL) * 16);
            uint4 q0 = up[0], q1 = up[1];
            float s = bf_lo(q1.w);
            s += p[0]  * bf_lo(q0.x); s += p[1]  * bf_hi(q0.x);
            s += p[2]  * bf_lo(q0.y); s += p[3]  * bf_hi(q0.y);
            s += p[4]  * bf_lo(q0.z); s += p[5]  * bf_hi(q0.z);
            s += p[6]  * bf_lo(q0.w); s += p[7]  * bf_hi(q0.w);
            s += p[8]  * bf_lo(q1.x); s += p[9]  * bf_hi(q1.x);
            s += p[10] * bf_lo(q1.y); s += p[11] * bf_hi(q1.y);
            s += p[12] * bf_lo(q1.z); s += p[13] * bf_hi(q1.z);
            acc1 += s;
        }
    }
    out[a * NH + j] = acc0;
    if (two) out[a * NH + j + JSL] = acc1;
}

// ---------- Fallback: direct per-(edge,h) with atomics ----------
__global__ void k_naive(const float* __restrict__ pf, const float* __restrict__ af,
                        const int* __restrict__ atp, const float* __restrict__ W,
                        const float* __restrict__ bias, float* __restrict__ out, int E)
{
    int idx = blockIdx.x * blockDim.x + threadIdx.x;
    if (idx >= E * NH) return;
    int e = idx / NH, h = idx - e * NH;
    int a0 = atp[2 * e], a1 = atp[2 * e + 1];
    float p[NPF];
    #pragma unroll
    for (int f = 0; f < NPF; ++f) p[f] = pf[(size_t)e * NPF + f];
    float acc = 0.f;
    for (int k = 0; k < NH; ++k) {
        float w = bias[h * NH + k];
        #pragma unroll
        for (int f = 0; f < NPF; ++f) w += p[f] * W[f * NW + h * NH + k];
        acc += w * af[a1 * NH + k];
    }
    atomicAdd(&out[a0 * NH + h], acc);
}

extern "C" void kernel_launch(void* const* d_in, const int* in_sizes, int n_in,
                              void* d_out, int out_size, void* d_ws, size_t ws_size,
                              hipStream_t stream) {
    const float* pf   = (const float*)d_in[0];
    const float* af   = (const float*)d_in[1];
    const int*   atp  = (const int*)d_in[2];
    const float* W    = (const float*)d_in[3];
    const float* bias = (const float*)d_in[4];
    float* out = (float*)d_out;
    const int E = in_sizes[2] / 2;

    const size_t offAfb = 0;
    const size_t offWbt = offAfb + (size_t)MROW * KP * 2;
    const size_t offU   = offWbt + (size_t)WROW * KP * 2;
    const size_t offRs  = offU + (size_t)NA * NCOL * 2;
    const size_t need   = offRs + (size_t)(NA + 1) * sizeof(int);

    if (ws_size >= need) {
        ushort* afb = (ushort*)((char*)d_ws + offAfb);
        ushort* wbt = (ushort*)((char*)d_ws + offWbt);
        ushort* U   = (ushort*)((char*)d_ws + offU);
        int*    rs  = (int*)((char*)d_ws + offRs);

        const int bA = (MROW * (KP / 4) + 255) / 256;   // 1027
        const int bW = (WROW * (KP / 4) + 255) / 256;   // 123
        const int bR = (E + 255) / 256;
        k_prep<<<bA + bW + bR, 256, 0, stream>>>(af, W, bias, atp, afb, wbt, rs, E, bA, bW);

        dim3 g1(NCOL / 80, MROW / 128);   // 15 x 79
        k_gemm<<<g1, 256, 0, stream>>>(afb, wbt, U);

        k_edges2<<<(NA * JSL + 255) / 256, 256, 0, stream>>>(pf, atp, rs, U, out);
    } else {
        hipMemsetAsync(d_out, 0, (size_t)out_size * sizeof(float), stream);
        k_naive<<<((size_t)E * NH + 255) / 256, 256, 0, stream>>>(pf, af, atp, W, bias, out, E);
    }
}

// Round 4
// 37.670 us; speedup vs baseline: 2.9586x; 1.1012x over previous
//
#include <hip/hip_runtime.h>
#include <hip/hip_bf16.h>
#include <stdint.h>

// Problem constants
constexpr int NA   = 10000;  // atoms
constexpr int NH   = 75;     // hidden
constexpr int NPF  = 14;     // pair features
constexpr int NW   = 5625;   // 75*75
constexpr int NCOL = 1200;   // 75*16: per h -> f=0..13 W-cols, f=14 bias, f=15 pad
constexpr int KP   = 104;    // K padded: 75 data, zeros to 96 (3 MFMA k-steps), 104 stride
constexpr int MROW = 10112;  // NA padded to 79*128
constexpr int WROW = 1208;   // NCOL padded rows for staging slack
constexpr int JSL  = 38;     // h-slots per atom in k_edges (thread does h=j and h=j+38)
constexpr int BN   = 240;    // gemm col-tile (15 n-frags), NCOL/BN = 5
constexpr int ACH  = 26;     // A staging chunks of 1024B (128*104*2 = 26624B)
constexpr int BCH  = 49;     // B staging chunks (240*104*2 = 49920B -> 49 w/ slack)

typedef _Float16 f16;
typedef __attribute__((ext_vector_type(2))) _Float16 f16x2;
typedef __attribute__((ext_vector_type(8))) _Float16 f16x8;
typedef __attribute__((ext_vector_type(4))) float floatx4;

__device__ __forceinline__ ushort f2h_bits(float f) {
    return __builtin_bit_cast(ushort, (f16)f);       // v_cvt_f16_f32, RNE
}
__device__ __forceinline__ f16x2 bch(uint32_t w) {
    return __builtin_bit_cast(f16x2, w);
}

__device__ __forceinline__ void gload16(const void* g, void* l) {
    __builtin_amdgcn_global_load_lds(
        (const __attribute__((address_space(1))) uint32_t*)g,
        (__attribute__((address_space(3))) uint32_t*)l, 16, 0, 0);
}

// 16-wide f16 dot via 8x v_dot2_f32_f16 (f32 accumulate)
__device__ __forceinline__ float dot16(uint4 p0, uint4 p1, uint4 u0, uint4 u1, float c) {
    c = __builtin_amdgcn_fdot2(bch(p0.x), bch(u0.x), c, false);
    c = __builtin_amdgcn_fdot2(bch(p0.y), bch(u0.y), c, false);
    c = __builtin_amdgcn_fdot2(bch(p0.z), bch(u0.z), c, false);
    c = __builtin_amdgcn_fdot2(bch(p0.w), bch(u0.w), c, false);
    c = __builtin_amdgcn_fdot2(bch(p1.x), bch(u1.x), c, false);
    c = __builtin_amdgcn_fdot2(bch(p1.y), bch(u1.y), c, false);
    c = __builtin_amdgcn_fdot2(bch(p1.z), bch(u1.z), c, false);
    c = __builtin_amdgcn_fdot2(bch(p1.w), bch(u1.w), c, false);
    return c;
}

// ---------- K0: fused prep: cvt_af | cvt_w | cvt_pf | rowstart ----------
__global__ __launch_bounds__(256) void k_prep(
    const float* __restrict__ af, const float* __restrict__ W,
    const float* __restrict__ bias, const float* __restrict__ pf,
    const int* __restrict__ atp,
    ushort* __restrict__ afb, ushort* __restrict__ wbt,
    ushort* __restrict__ pfh, int* __restrict__ rs,
    int E, int bA, int bW, int bP)
{
    const int b = blockIdx.x, tid = threadIdx.x;
    if (b < bA) {
        // af -> f16 [MROW][KP], zero padded
        int idx = b * 256 + tid;
        if (idx >= MROW * (KP / 4)) return;
        int a = idx / (KP / 4), q = idx - a * (KP / 4);
        int k0 = q * 4;
        ushort4 st = {0, 0, 0, 0};
        if (a < NA) {
            float v[4];
            #pragma unroll
            for (int j = 0; j < 4; ++j) {
                int k = k0 + j;
                v[j] = (k < NH) ? af[a * NH + k] : 0.f;
            }
            st.x = f2h_bits(v[0]); st.y = f2h_bits(v[1]);
            st.z = f2h_bits(v[2]); st.w = f2h_bits(v[3]);
        }
        ((ushort4*)afb)[idx] = st;
    } else if (b < bA + bW) {
        // Wbt[c][k] f16, c = h*16+f (N-major)
        int idx = (b - bA) * 256 + tid;
        if (idx >= WROW * (KP / 4)) return;
        int c = idx / (KP / 4), q = idx - c * (KP / 4);
        int k0 = q * 4;
        ushort4 st = {0, 0, 0, 0};
        if (c < NCOL) {
            int h = c >> 4, f = c & 15;
            float v[4] = {0.f, 0.f, 0.f, 0.f};
            #pragma unroll
            for (int j = 0; j < 4; ++j) {
                int k = k0 + j;
                if (k < NH) {
                    if (f < NPF)       v[j] = W[f * NW + h * NH + k];
                    else if (f == NPF) v[j] = bias[h * NH + k];
                }
            }
            st.x = f2h_bits(v[0]); st.y = f2h_bits(v[1]);
            st.z = f2h_bits(v[2]); st.w = f2h_bits(v[3]);
        }
        ((ushort4*)wbt)[idx] = st;
    } else if (b < bA + bW + bP) {
        // pf -> f16x16 per edge, slot14 = 1.0 (bias), slot15 = 0
        int e = (b - bA - bW) * 256 + tid;
        if (e >= E) return;
        const float* pfe = pf + (size_t)e * NPF;
        union { f16 h[16]; uint4 q[2]; } u;
        #pragma unroll
        for (int f = 0; f < 7; ++f) {
            float2 t = *(const float2*)&pfe[2 * f];
            u.h[2 * f]     = (f16)t.x;
            u.h[2 * f + 1] = (f16)t.y;
        }
        u.h[14] = (f16)1.0f;
        u.h[15] = (f16)0.0f;
        uint4* dst = (uint4*)(pfh + (size_t)e * 16);
        dst[0] = u.q[0]; dst[1] = u.q[1];
    } else {
        // rowstart CSR from sorted atom_to_pair[:,0]
        int e = (b - bA - bW - bP) * 256 + tid;
        if (e >= E) return;
        int c  = atp[2 * e];
        int cp = (e == 0) ? -1 : atp[2 * (e - 1)];
        for (int a = cp + 1; a <= c; ++a) rs[a] = e;
        if (e == E - 1)
            for (int a = c + 1; a <= NA; ++a) rs[a] = E;
    }
}

// ---------- K1: MFMA GEMM  U[a][c] = sum_k afb[a][k]*Wbt[c][k], U stored f16 ----------
// Tile 128x240, 4 waves: wave w owns rows w*32..+31 (2 a-frags) x 240 cols (15 c-frags).
// mfma(w_frag, a_frag): D col (lane&15) = a-dim, D reg-axis = c-dim -> 8B stores.
__global__ __launch_bounds__(256, 2) void k_gemm(const ushort* __restrict__ afb,
                                                 const ushort* __restrict__ wbt,
                                                 ushort* __restrict__ U) {
    __shared__ __align__(16) ushort sm[38400];         // 26624B A + 50176B B
    ushort* As = sm;                                   // [128][104]
    ushort* Bs = sm + 13312;                           // [~241][104]

    const int tid  = threadIdx.x;
    const int lane = tid & 63, wid = tid >> 6;
    const int a0 = blockIdx.y * 128;
    const int c0 = blockIdx.x * BN;

    const char* aSrc = (const char*)(afb + (size_t)a0 * KP);
    const char* bSrc = (const char*)(wbt + (size_t)c0 * KP);

    for (int c = wid; c < ACH + BCH; c += 4) {
        if (c < ACH) gload16(aSrc + c * 1024 + lane * 16, (char*)As + c * 1024);
        else {
            int cb = c - ACH;
            gload16(bSrc + cb * 1024 + lane * 16, (char*)Bs + cb * 1024);
        }
    }
    __syncthreads();

    const int lr = lane & 15;          // frag row; D col
    const int lk = (lane >> 4) * 8;    // frag k-base
    floatx4 acc[15][2] = {};

    #pragma unroll
    for (int ks = 0; ks < 3; ++ks) {
        f16x8 a[2], bv[15];
        #pragma unroll
        for (int mf = 0; mf < 2; ++mf)
            a[mf] = *(const f16x8*)&As[(wid * 32 + mf * 16 + lr) * KP + ks * 32 + lk];
        #pragma unroll
        for (int nf = 0; nf < 15; ++nf)
            bv[nf] = *(const f16x8*)&Bs[(nf * 16 + lr) * KP + ks * 32 + lk];
        #pragma unroll
        for (int nf = 0; nf < 15; ++nf)
            #pragma unroll
            for (int mf = 0; mf < 2; ++mf)
                acc[nf][mf] = __builtin_amdgcn_mfma_f32_16x16x32_f16(
                    bv[nf], a[mf], acc[nf][mf], 0, 0, 0);
    }

    // D: col=lane&15 -> a-row; reg-axis -> 4 consecutive c
    #pragma unroll
    for (int mf = 0; mf < 2; ++mf) {
        int arow = a0 + wid * 32 + mf * 16 + lr;
        if (arow >= NA) continue;
        #pragma unroll
        for (int nf = 0; nf < 15; ++nf) {
            int cbase = c0 + nf * 16 + (lane >> 4) * 4;
            uint2 st;
            st.x = __builtin_bit_cast(uint32_t,
                     __builtin_amdgcn_cvt_pkrtz(acc[nf][mf][0], acc[nf][mf][1]));
            st.y = __builtin_bit_cast(uint32_t,
                     __builtin_amdgcn_cvt_pkrtz(acc[nf][mf][2], acc[nf][mf][3]));
            *(uint2*)&U[(size_t)arow * NCOL + cbase] = st;
        }
    }
}

// ---------- K2: per-(atom, j) edge loop; thread handles h=j and h=j+38 ----------
__global__ __launch_bounds__(256) void k_edges2(
    const ushort* __restrict__ pfh, const int* __restrict__ atp,
    const int* __restrict__ rs, const ushort* __restrict__ U,
    float* __restrict__ out)
{
    int idx = blockIdx.x * blockDim.x + threadIdx.x;
    if (idx >= NA * JSL) return;
    int a = idx / JSL;
    int j = idx - a * JSL;
    const bool two = (j + JSL) < NH;   // j < 37
    int e0 = rs[a], e1 = rs[a + 1];

    float acc0 = 0.f, acc1 = 0.f;
    for (int e = e0; e < e1; ++e) {
        int a1 = atp[2 * e + 1];
        const uint4* pq = (const uint4*)(pfh + (size_t)e * 16);
        uint4 p0 = pq[0], p1 = pq[1];
        const ushort* ub = U + (size_t)a1 * NCOL;
        {
            const uint4* up = (const uint4*)(ub + j * 16);
            acc0 = dot16(p0, p1, up[0], up[1], acc0);
        }
        if (two) {
            const uint4* up = (const uint4*)(ub + (j + JSL) * 16);
            acc1 = dot16(p0, p1, up[0], up[1], acc1);
        }
    }
    out[a * NH + j] = acc0;
    if (two) out[a * NH + j + JSL] = acc1;
}

// ---------- Fallback: direct per-(edge,h) with atomics (fp32) ----------
__global__ void k_naive(const float* __restrict__ pf, const float* __restrict__ af,
                        const int* __restrict__ atp, const float* __restrict__ W,
                        const float* __restrict__ bias, float* __restrict__ out, int E)
{
    int idx = blockIdx.x * blockDim.x + threadIdx.x;
    if (idx >= E * NH) return;
    int e = idx / NH, h = idx - e * NH;
    int a0 = atp[2 * e], a1 = atp[2 * e + 1];
    float p[NPF];
    #pragma unroll
    for (int f = 0; f < NPF; ++f) p[f] = pf[(size_t)e * NPF + f];
    float acc = 0.f;
    for (int k = 0; k < NH; ++k) {
        float w = bias[h * NH + k];
        #pragma unroll
        for (int f = 0; f < NPF; ++f) w += p[f] * W[f * NW + h * NH + k];
        acc += w * af[a1 * NH + k];
    }
    atomicAdd(&out[a0 * NH + h], acc);
}

extern "C" void kernel_launch(void* const* d_in, const int* in_sizes, int n_in,
                              void* d_out, int out_size, void* d_ws, size_t ws_size,
                              hipStream_t stream) {
    const float* pf   = (const float*)d_in[0];
    const float* af   = (const float*)d_in[1];
    const int*   atp  = (const int*)d_in[2];
    const float* W    = (const float*)d_in[3];
    const float* bias = (const float*)d_in[4];
    float* out = (float*)d_out;
    const int E = in_sizes[2] / 2;

    const size_t offAfb = 0;
    const size_t offWbt = offAfb + (size_t)MROW * KP * 2;
    const size_t offU   = offWbt + (size_t)WROW * KP * 2;
    const size_t offPfh = offU + (size_t)NA * NCOL * 2;
    const size_t offRs  = offPfh + (size_t)E * 16 * 2;
    const size_t need   = offRs + (size_t)(NA + 1) * sizeof(int);

    if (ws_size >= need) {
        ushort* afb = (ushort*)((char*)d_ws + offAfb);
        ushort* wbt = (ushort*)((char*)d_ws + offWbt);
        ushort* U   = (ushort*)((char*)d_ws + offU);
        ushort* pfh = (ushort*)((char*)d_ws + offPfh);
        int*    rs  = (int*)((char*)d_ws + offRs);

        const int bA = (MROW * (KP / 4) + 255) / 256;   // 1027
        const int bW = (WROW * (KP / 4) + 255) / 256;   // 123
        const int bP = (E + 255) / 256;                 // 250
        const int bR = (E + 255) / 256;                 // 250
        k_prep<<<bA + bW + bP + bR, 256, 0, stream>>>(af, W, bias, pf, atp,
                                                      afb, wbt, pfh, rs, E, bA, bW, bP);

        dim3 g1(NCOL / BN, MROW / 128);   // 5 x 79
        k_gemm<<<g1, 256, 0, stream>>>(afb, wbt, U);

        k_edges2<<<(NA * JSL + 255) / 256, 256, 0, stream>>>(pfh, atp, rs, U, out);
    } else {
        hipMemsetAsync(d_out, 0, (size_t)out_size * sizeof(float), stream);
        k_naive<<<((size_t)E * NH + 255) / 256, 256, 0, stream>>>(pf, af, atp, W, bias, out, E);
    }
}